// Round 19
// baseline (131.381 us; speedup 1.0000x reference)
//
#include <hip/hip_runtime.h>
#include <hip/hip_bf16.h>

#define NB 32
#define NN 128
#define NE 16256
#define ND 64
#define NHID 128
#define NM 128
#define NOH 256
#define NT 2
#define EHALF 8128
#define NTILE 127        // 64-edge tiles per half (127*64 == 8128 exactly)
#define TILE_E 64

typedef short s16x8 __attribute__((ext_vector_type(8)));
typedef short s16x4 __attribute__((ext_vector_type(4)));
typedef float f32x4 __attribute__((ext_vector_type(4)));

#define MFMA16(a, b, c) __builtin_amdgcn_mfma_f32_16x16x32_bf16((a), (b), (c), 0, 0, 0)

// ---- ws layout (bytes) ----
// partial: bf16 [256][m=128][n=128]
#define PARTIAL_SZ ((size_t)256 * 128 * 128 * 2)          //  8,388,608
#define WS_RS      (PARTIAL_SZ)                           // ushort[NE][128]
#define RS_SZ      ((size_t)NE * 128 * 2)                 //  4,161,536
#define WS_RRT     (WS_RS + RS_SZ)                        // ushort[128][NE]
#define RRT_SZ     ((size_t)128 * NE * 2)                 //  4,161,536
#define WS_IWA     (WS_RRT + RRT_SZ)                      // ushort[b][half][it][h=128][n=128]
#define IWA_SZ     ((size_t)NB * 2 * 2 * 128 * 128 * 2)   //  8,388,608
#define WS_OW      (WS_IWA + IWA_SZ)                      // frag-ordered bf16 node weights
#define OW_SZ      ((size_t)(32768 + 65536 + 16384) * 2)  //    229,376
// total = 25.3 MB (<= proven 32 MB)

__device__ __forceinline__ ushort f2bf(float x) {
    uint u = __float_as_uint(x);
    return (ushort)((u + 0x7fffu + ((u >> 16) & 1u)) >> 16);
}
__device__ __forceinline__ float bf2f(ushort h) {
    return __uint_as_float(((uint)h) << 16);
}
__device__ __forceinline__ float4 ldg4(const float* p) {
    return *reinterpret_cast<const float4*>(p);
}
// pack 2 f32 -> 2 bf16 in one dword (RNE), single VALU op; low word = first arg
__device__ __forceinline__ uint cvtpk(float lo, float hi) {
    uint r;
    asm("v_cvt_pk_bf16_f32 %0, %1, %2" : "=v"(r) : "v"(lo), "v"(hi));
    return r;
}
__device__ __forceinline__ ushort f2bf1(float x) {   // single value via cvt_pk
    return (ushort)cvtpk(x, 0.f);
}
// pack 8 f32 (two float4) -> s16x8 bf16 via cvt_pk (uint4 is addressable)
__device__ __forceinline__ s16x8 pack8(float4 u, float4 v) {
    uint4 o;
    o.x = cvtpk(u.x, u.y);
    o.y = cvtpk(u.z, u.w);
    o.z = cvtpk(v.x, v.y);
    o.w = cvtpk(v.z, v.w);
    return *(s16x8*)&o;
}
// full-granule XOR swizzle for 256B rows: byte ^= (row&15)<<4
__device__ __forceinline__ char* swz16(void* base, int row, int bir) {
    return (char*)base + row * 256 + (bir ^ ((row & 15) << 4));
}
__device__ __forceinline__ const char* swz16c(const void* base, int row, int bir) {
    return (const char*)base + row * 256 + (bir ^ ((row & 15) << 4));
}
// 8-granule XOR swizzle for 128B rows: byte ^= (row&7)<<4
__device__ __forceinline__ char* swz8(void* base, int row, int bir) {
    return (char*)base + row * 128 + (bir ^ ((row & 7) << 4));
}
__device__ __forceinline__ const char* swz8c(const void* base, int row, int bir) {
    return (const char*)base + row * 128 + (bir ^ ((row & 7) << 4));
}
// generic-rowBytes variant (k_out buffers)
__device__ __forceinline__ char* swzR(void* base, int row, int rowBytes, int bir) {
    return (char*)base + row * rowBytes + (bir ^ ((row & 15) << 4));
}
__device__ __forceinline__ const char* swzRc(const void* base, int row, int rowBytes, int bir) {
    return (const char*)base + row * rowBytes + (bir ^ ((row & 15) << 4));
}
// async 16B global->LDS (dest lane-linear; source pre-swizzled per G21)
__device__ __forceinline__ void gload16(const void* g, void* l) {
    __builtin_amdgcn_global_load_lds(
        (const __attribute__((address_space(1))) void*)g,
        (__attribute__((address_space(3))) void*)l, 16, 0, 0);
}
// T4 primitives: LDS-only barrier (VMEM stays in flight) + counted vmcnt
__device__ __forceinline__ void bar_lgkm() {
    asm volatile("s_waitcnt lgkmcnt(0)" ::: "memory");
    __builtin_amdgcn_sched_barrier(0);
    __builtin_amdgcn_s_barrier();
    __builtin_amdgcn_sched_barrier(0);
}
#define WAIT_VM(N) do { \
    asm volatile("s_waitcnt vmcnt(" #N ")" ::: "memory"); \
    __builtin_amdgcn_sched_barrier(0); \
} while (0)

// ---------------------------------------------------------------------------
// k_pre: balanced 256-block grid (1 block/CU, no straggler round).
// blocks 0..63:   rrT transpose, 2 eb each (127 total)
// blocks 64..95:  rs convert, 4 eb each
// blocks 96..223: inpWA precompute (128)
// blocks 224..255: node weights frag-order, 32 slices
// ---------------------------------------------------------------------------
__global__ __launch_bounds__(256)
void k_pre(const float* __restrict__ inputs,
           const float* __restrict__ rel_rec, const float* __restrict__ rel_send,
           const float* __restrict__ w1, const float* __restrict__ w3,
           const float* __restrict__ ow1, const float* __restrict__ ow2,
           const float* __restrict__ ow3,
           char* __restrict__ ws)
{
    ushort* rs  = (ushort*)(ws + WS_RS);
    ushort* rrT = (ushort*)(ws + WS_RRT);
    const int t = threadIdx.x;
    const int blk = blockIdx.x;

    if (blk < 64) {                        // rrT: 1-pass transpose, 2 eb/block
        __shared__ ushort tl[128][130];    // pad 2 -> 260B rows
        for (int rep = 0; rep < 2; ++rep) {
            const int eb = blk * 2 + rep;
            if (eb >= 127) break;          // uniform across block
            if (rep) __syncthreads();      // protect tl reuse
            for (int i = t; i < 4096; i += 256) {
                const int e = i >> 5, nq = i & 31;
                float4 v = ldg4(rel_rec + (size_t)(eb * 128 + e) * 128 + nq * 4);
                uint2 o;
                o.x = cvtpk(v.x, v.y);
                o.y = cvtpk(v.z, v.w);
                *(uint2*)&tl[e][nq * 4] = o;
            }
            __syncthreads();
            const int n = t >> 1, part = t & 1;
            for (int c = 0; c < 8; ++c) {
                const int e0 = part * 64 + c * 8;
                s16x8 v;
#pragma unroll
                for (int j = 0; j < 8; ++j) v[j] = (short)tl[e0 + j][n];
                *(s16x8*)&rrT[(size_t)n * NE + eb * 128 + e0] = v;
            }
        }
    } else if (blk < 96) {                 // rs: straight convert, 4 eb/block
        for (int j = 0; j < 4; ++j) {
            const int eb = (blk - 64) * 4 + j;
            if (eb >= 127) break;
            const float4* src = (const float4*)(rel_send + (size_t)eb * 16384);
            for (int i = t; i < 4096; i += 256) {
                float4 v = src[i];
                uint2 o;
                o.x = cvtpk(v.x, v.y);
                o.y = cvtpk(v.z, v.w);
                *(uint2*)(rs + (size_t)eb * 16384 + (size_t)i * 4) = o;
            }
        }
    } else if (blk < 224) {                // inpWA precompute (MFMA)
        ushort* iwa = (ushort*)(ws + WS_IWA);
        const int wg = blk - 96;           // 0..127
        const int b = wg >> 2, half = (wg >> 1) & 1, it = wg & 1;
        const float* WA  = (half ? w3 : w1) + (size_t)it * NHID * ND;
        const float* inp = inputs + (size_t)b * NN * ND;
        ushort* dst = iwa + (size_t)wg * NHID * NN;    // [h][n]

        const int lane = t & 63, wave = t >> 6;
        const int l16 = lane & 15, l4 = lane >> 4;

        for (int hh = 0; hh < 2; ++hh) {
            const int ht = wave * 2 + hh;
            s16x8 bf[2];
#pragma unroll
            for (int ks = 0; ks < 2; ++ks) {
                const float* p = WA + (size_t)(ht * 16 + l16) * ND + ks * 32 + l4 * 8;
                bf[ks] = pack8(ldg4(p), ldg4(p + 4));
            }
            for (int nt = 0; nt < 8; ++nt) {
                s16x8 af[2];
#pragma unroll
                for (int ks = 0; ks < 2; ++ks) {
                    const float* p = inp + (size_t)(nt * 16 + l16) * ND + ks * 32 + l4 * 8;
                    af[ks] = pack8(ldg4(p), ldg4(p + 4));
                }
                f32x4 c = (f32x4){0.f, 0.f, 0.f, 0.f};
                c = MFMA16(af[0], bf[0], c);
                c = MFMA16(af[1], bf[1], c);
                uint2 o;
                o.x = cvtpk(c[0], c[1]);
                o.y = cvtpk(c[2], c[3]);
                *(uint2*)&dst[(size_t)(ht * 16 + l16) * NN + nt * 16 + l4 * 4] = o;
            }
        }
    } else {                               // node weights -> bf16, 32 slices
        ushort* owbf = (ushort*)(ws + WS_OW);
        const int sl = blk - 224;          // 0..31
        if (t < 128) {
            const int i = sl * 128 + t;
            const int ln = i & 63, ks = (i >> 6) & 3, ot = i >> 8;
            const float* src = ow1 + (size_t)(ot * 16 + (ln & 15)) * 128 + ks * 32 + (ln >> 4) * 8;
            ushort* d = owbf + (size_t)i * 8;
#pragma unroll
            for (int j = 0; j < 8; ++j) d[j] = f2bf(src[j]);
        }
        {
            const int i = sl * 256 + t;
            const int ln = i & 63, ks = (i >> 6) & 7, ot = i >> 9;
            const float* src = ow2 + (size_t)(ot * 16 + (ln & 15)) * 256 + ks * 32 + (ln >> 4) * 8;
            ushort* d = owbf + 32768 + (size_t)i * 8;
#pragma unroll
            for (int j = 0; j < 8; ++j) d[j] = f2bf(src[j]);
        }
        if (t < 64) {
            const int i = sl * 64 + t;
            const int ln = i & 63, ks = (i >> 6) & 7, dt = i >> 9;
            const float* src = ow3 + (size_t)(dt * 16 + (ln & 15)) * 256 + ks * 32 + (ln >> 4) * 8;
            ushort* d = owbf + 98304 + (size_t)i * 8;
#pragma unroll
            for (int j = 0; j < 8; ++j) d[j] = f2bf(src[j]);
        }
    }
}

// ---------------------------------------------------------------------------
// k_edge: round-16 structure + T4 counted-vmcnt barriers.
//   P(t): rt stage (oldest vmem); WAIT_VM(0) [rs(t) retired];
//         issue rr(t), rs(t+1) gloads; H phase            | bar_lgkm (bar1)
//   M(t): M phase; WAIT_VM(2|0) [rr(t) retired,
//         rs(t+1) stays in flight]                        | bar_lgkm (bar2)
//   agg(t): agg += rrT@Mt[0] + rrT@Mt[1]
// grid 256 = b*8 + half*4 + chunk(4), block 512.
// ---------------------------------------------------------------------------
__global__ __launch_bounds__(512, 1)
void k_edge(const float* __restrict__ rel_type,
            const float* __restrict__ b1, const float* __restrict__ b2,
            const float* __restrict__ b3, const float* __restrict__ b4,
            const float* __restrict__ w2, const float* __restrict__ w4,
            char* __restrict__ ws)
{
    const ushort* rsg = (const ushort*)(ws + WS_RS);
    const ushort* rrT = (const ushort*)(ws + WS_RRT);
    const ushort* iwa = (const ushort*)(ws + WS_IWA);
    ushort* partial   = (ushort*)ws;

    const int tid  = threadIdx.x;
    const int wave = tid >> 6;
    const int lane = tid & 63;
    const int l16  = lane & 15;
    const int l4   = lane >> 4;
    const int wi   = wave & 1;     // it for H/M phases
    const int wg2  = wave >> 1;    // 32-col block for H/M phases
    const int wn   = wave & 3;     // agg: n-block (32 rows)
    const int wm2  = wave >> 2;    // agg: m-half (64 cols)

    const int wg    = blockIdx.x;
    const int b     = wg >> 3;
    const int half  = (wg >> 2) & 1;
    const int chunk = wg & 3;

    const float* BA    = half ? b3 : b1;
    const float* BB    = half ? b4 : b2;
    const float* WBsrc = half ? w4 : w2;

    __shared__ ushort H_s[2][64 * 128];     // 32 KB [it][e][h], 256B rows
    __shared__ ushort rs_s[2][64 * 128];    // 32 KB, 256B rows
    __shared__ ushort rr_s[2][128 * 64];    // 32 KB, 128B rows
    __shared__ ushort Mt_s[2][128 * 64];    // 32 KB [it][m][e], 128B rows
    __shared__ float  rt_s[2][128];         //  1 KB

    // persistent fragments: wIW 32 (only it=wi) + wB 32 (only it=wi) + agg 32
    s16x8 wIW[2][4];   // [ht][ks]: A-frag rows h = wg2*32 + ht*16 + l16, k=n
    {
        const ushort* iwb = iwa + (size_t)((b * 2 + half) * 2 + wi) * NHID * NN;
#pragma unroll
        for (int ht = 0; ht < 2; ++ht)
#pragma unroll
            for (int ks = 0; ks < 4; ++ks)
                wIW[ht][ks] = *(const s16x8*)(iwb +
                    (size_t)(wg2 * 32 + ht * 16 + l16) * NN + ks * 32 + l4 * 8);
    }
    s16x8 wB[2][4];    // [mt][ks], m = wg2*32 + mt*16 + l16, it = wi
#pragma unroll
    for (int mt = 0; mt < 2; ++mt)
#pragma unroll
        for (int ks = 0; ks < 4; ++ks) {
            const float* p = WBsrc +
                (size_t)(wi * NM + wg2 * 32 + mt * 16 + l16) * NHID + ks * 32 + l4 * 8;
            wB[mt][ks] = pack8(ldg4(p), ldg4(p + 4));
        }
    // biasA per-reg (h = wg2*32 + ht*16 + l4*4 + r) as float4; biasB per-lane
    float4 bA[2];
#pragma unroll
    for (int ht = 0; ht < 2; ++ht)
        bA[ht] = ldg4(BA + wi * NHID + wg2 * 32 + ht * 16 + l4 * 4);
    float biasB[2];
#pragma unroll
    for (int q = 0; q < 2; ++q)
        biasB[q] = BB[wi * NM + wg2 * 32 + q * 16 + l16];

    f32x4 agg[2][4];   // [nt][mt]: rows wn*32+nt*16, cols wm2*64+mt*16
#pragma unroll
    for (int i = 0; i < 2; ++i)
#pragma unroll
        for (int j = 0; j < 4; ++j) agg[i][j] = (f32x4){0.f, 0.f, 0.f, 0.f};

    const int t0 = chunk * 32;
    const int t1 = (t0 + 32 < NTILE) ? (t0 + 32) : NTILE;

    // ---- prologue: stage rs(t0) into buf0, full drain once ----
    {
        const int ebase0 = half * EHALF + t0 * TILE_E;
#pragma unroll
        for (int s = 0; s < 2; ++s) {
            const int i = s * 512 + tid;
            const int e = i >> 4, c = i & 15;
            const int cp = c ^ (e & 15);
            gload16(rsg + (size_t)(ebase0 + e) * 128 + cp * 8, (char*)&rs_s[0][0] + i * 16);
        }
    }
    __syncthreads();

    for (int t = t0; t < t1; ++t) {
        const int buf  = (t - t0) & 1;
        const int nbuf = buf ^ 1;
        const int ebase = half * EHALF + t * TILE_E;
        const bool do_next = (t + 1) < t1;

        // ---- P(t) ----
        // (a) rt stage FIRST (oldest vmem op of this tile)
        if (tid < 128)
            rt_s[buf][tid] = rel_type[((size_t)b * NE + ebase + (tid >> 1)) * NT + (tid & 1)];
        // (b) ensure rs(t) gloads (issued last tile) retired before rs_s reads;
        //     issued-this-tile loads come AFTER this wait.
        WAIT_VM(0);
        // (c) issue rr(t) -> rr_s[buf] (consumed after bar2)
#pragma unroll
        for (int s = 0; s < 2; ++s) {
            const int j = s * 512 + tid;
            const int n = j >> 3, c = j & 7;
            const int cp = c ^ (n & 7);
            gload16(rrT + (size_t)n * NE + ebase + cp * 8, (char*)&rr_s[buf][0] + j * 16);
        }
        // (d) issue rs(t+1) -> rs_s[nbuf] (consumed in P(t+1) H phase)
        if (do_next) {
            const int ebn = ebase + TILE_E;
#pragma unroll
            for (int s = 0; s < 2; ++s) {
                const int i = s * 512 + tid;
                const int e = i >> 4, c = i & 15;
                const int cp = c ^ (e & 15);
                gload16(rsg + (size_t)(ebn + e) * 128 + cp * 8, (char*)&rs_s[nbuf][0] + i * 16);
            }
        }

        // (e) H phase (SWAPPED): C[h][e] = mfma(A=wIW, B=rs); uint2 h-contig
#pragma unroll
        for (int et = 0; et < 4; ++et) {
            const int erow = et * 16 + l16;
            s16x8 rb0 = *(const s16x8*)swz16c(&rs_s[buf][0], erow, 0 * 64 + l4 * 16);
            s16x8 rb1 = *(const s16x8*)swz16c(&rs_s[buf][0], erow, 1 * 64 + l4 * 16);
            s16x8 rb2 = *(const s16x8*)swz16c(&rs_s[buf][0], erow, 2 * 64 + l4 * 16);
            s16x8 rb3 = *(const s16x8*)swz16c(&rs_s[buf][0], erow, 3 * 64 + l4 * 16);
#pragma unroll
            for (int ht = 0; ht < 2; ++ht) {
                f32x4 c = (f32x4){0.f, 0.f, 0.f, 0.f};
                __builtin_amdgcn_s_setprio(1);
                c = MFMA16(wIW[ht][0], rb0, c);
                c = MFMA16(wIW[ht][1], rb1, c);
                c = MFMA16(wIW[ht][2], rb2, c);
                c = MFMA16(wIW[ht][3], rb3, c);
                __builtin_amdgcn_s_setprio(0);
                uint2 v;
                v.x = cvtpk(fmaxf(c[0] + bA[ht].x, 0.f), fmaxf(c[1] + bA[ht].y, 0.f));
                v.y = cvtpk(fmaxf(c[2] + bA[ht].z, 0.f), fmaxf(c[3] + bA[ht].w, 0.f));
                *(uint2*)swz16(&H_s[wi][0], erow, (wg2 * 32 + ht * 16 + l4 * 4) * 2) = v;
            }
        }
        bar_lgkm();                                        // bar1 (vmem in flight)

        // ---- M(t): Mpart[wi][:, wg2*32..+32]; reads only H[wi] ----
#pragma unroll
        for (int et = 0; et < 4; ++et) {
            const int e = et * 16 + l16;
            s16x8 a0 = *(const s16x8*)swz16c(&H_s[wi][0], e, 0 * 64 + l4 * 16);
            s16x8 a1 = *(const s16x8*)swz16c(&H_s[wi][0], e, 1 * 64 + l4 * 16);
            s16x8 a2 = *(const s16x8*)swz16c(&H_s[wi][0], e, 2 * 64 + l4 * 16);
            s16x8 a3 = *(const s16x8*)swz16c(&H_s[wi][0], e, 3 * 64 + l4 * 16);
            float rtv[4];
#pragma unroll
            for (int r = 0; r < 4; ++r)
                rtv[r] = rt_s[buf][(et * 16 + l4 * 4 + r) * 2 + wi];
#pragma unroll
            for (int mt = 0; mt < 2; ++mt) {
                f32x4 c = (f32x4){0.f, 0.f, 0.f, 0.f};
                __builtin_amdgcn_s_setprio(1);
                c = MFMA16(a0, wB[mt][0], c);
                c = MFMA16(a1, wB[mt][1], c);
                c = MFMA16(a2, wB[mt][2], c);
                c = MFMA16(a3, wB[mt][3], c);
                __builtin_amdgcn_s_setprio(0);
                const int m = wg2 * 32 + mt * 16 + l16;
                uint2 v;
                v.x = cvtpk(fmaxf(c[0] + biasB[mt], 0.f) * rtv[0],
                            fmaxf(c[1] + biasB[mt], 0.f) * rtv[1]);
                v.y = cvtpk(fmaxf(c[2] + biasB[mt], 0.f) * rtv[2],
                            fmaxf(c[3] + biasB[mt], 0.f) * rtv[3]);
                *(uint2*)swz8(&Mt_s[wi][0], m, et * 32 + l4 * 8) = v;
            }
        }
        // retire rr(t) (keep rs(t+1) in flight when present)
        if (do_next) { WAIT_VM(2); } else { WAIT_VM(0); }
        bar_lgkm();                                        // bar2

        // ---- agg(t): agg += rrT@Mt[0] + rrT@Mt[1]  (32n x 64m per wave) ----
#pragma unroll
        for (int ks = 0; ks < 2; ++ks) {
            s16x8 aa0 = *(const s16x8*)swz8c(&rr_s[buf][0], wn * 32 + 0 * 16 + l16, ks * 64 + l4 * 16);
            s16x8 aa1 = *(const s16x8*)swz8c(&rr_s[buf][0], wn * 32 + 1 * 16 + l16, ks * 64 + l4 * 16);
#pragma unroll
            for (int it = 0; it < 2; ++it) {
                __builtin_amdgcn_s_setprio(1);
#pragma unroll
                for (int mt = 0; mt < 4; ++mt) {
                    s16x8 bb = *(const s16x8*)swz8c(&Mt_s[it][0],
                        wm2 * 64 + mt * 16 + l16, ks * 64 + l4 * 16);
                    agg[0][mt] = MFMA16(aa0, bb, agg[0][mt]);
                    agg[1][mt] = MFMA16(aa1, bb, agg[1][mt]);
                }
                __builtin_amdgcn_s_setprio(0);
            }
        }
    }

    // store bf16 partialT [wg][m][n]
    {
        ushort* dst = partial + (size_t)wg * (NN * NM);
#pragma unroll
        for (int nt = 0; nt < 2; ++nt)
#pragma unroll
            for (int mt = 0; mt < 4; ++mt) {
                const int m  = wm2 * 64 + mt * 16 + l16;
                const int n0 = wn * 32 + nt * 16 + l4 * 4;
                uint2 v;
                v.x = cvtpk(agg[nt][mt][0], agg[nt][mt][1]);
                v.y = cvtpk(agg[nt][mt][2], agg[nt][mt][3]);
                *(uint2*)&dst[(size_t)m * NN + n0] = v;
            }
    }
}

// ---------------------------------------------------------------------------
// k_out: MFMA node MLP, 512 threads (8 waves, 2/SIMD), frag-ordered weights.
// grid 256 = b*8 + ng (16 n-rows). L1/L2: wave owns 2 o-tiles; L3: waves 0-3.
// ---------------------------------------------------------------------------
__global__ __launch_bounds__(512)
void k_out(const ushort* __restrict__ partial,
           const ushort* __restrict__ owbf,
           const float* __restrict__ inputs,
           const float* __restrict__ ob1, const float* __restrict__ ob2,
           const float* __restrict__ ob3,
           float* __restrict__ out)
{
    const int t    = threadIdx.x;
    const int wave = t >> 6;
    const int lane = t & 63;
    const int l16  = lane & 15;
    const int l4   = lane >> 4;
    const int wg   = blockIdx.x;
    const int b    = wg >> 3;
    const int n0   = (wg & 7) * 16;

    __shared__ ushort xA[16 * 128];    // 4 KB  [n][m], 256B rows
    __shared__ ushort h1A[16 * 256];   // 8 KB  [n][o], 512B rows
    __shared__ ushort h2A[16 * 256];   // 8 KB

    // reduce 8 bf16 partials -> xA (512 threads cover all 128m x 4 n-quads)
    {
        const int m = t >> 2, g = t & 3;
        float s0 = 0.f, s1 = 0.f, s2 = 0.f, s3 = 0.f;
#pragma unroll
        for (int c = 0; c < 8; ++c) {
            const ushort* p = partial + ((size_t)(b * 8 + c)) * (NN * NM) +
                              (size_t)m * NN + n0 + g * 4;
            s16x4 v = *(const s16x4*)p;
            s0 += bf2f((ushort)v[0]); s1 += bf2f((ushort)v[1]);
            s2 += bf2f((ushort)v[2]); s3 += bf2f((ushort)v[3]);
        }
        *(ushort*)swzR(xA, g * 4 + 0, 256, m * 2) = f2bf(s0);
        *(ushort*)swzR(xA, g * 4 + 1, 256, m * 2) = f2bf(s1);
        *(ushort*)swzR(xA, g * 4 + 2, 256, m * 2) = f2bf(s2);
        *(ushort*)swzR(xA, g * 4 + 3, 256, m * 2) = f2bf(s3);
    }
    __syncthreads();

    // L1: h1 = relu(x @ ow1^T + ob1); wave owns o-tiles {wave*2, wave*2+1}
    {
        s16x8 ka[4];
#pragma unroll
        for (int ks = 0; ks < 4; ++ks)
            ka[ks] = *(const s16x8*)swzRc(xA, l16, 256, ks * 64 + l4 * 16);
#pragma unroll
        for (int ot = 0; ot < 2; ++ot) {
            const int otg = wave * 2 + ot;
            const int o = otg * 16 + l16;
            f32x4 c = (f32x4){0.f, 0.f, 0.f, 0.f};
#pragma unroll
            for (int ks = 0; ks < 4; ++ks) {
                s16x8 wb = *(const s16x8*)&owbf[((size_t)(otg * 4 + ks) * 64 + lane) * 8];
                c = MFMA16(ka[ks], wb, c);
            }
            const float bias = ob1[o];
#pragma unroll
            for (int r = 0; r < 4; ++r)
                *(ushort*)swzR(h1A, l4 * 4 + r, 512, o * 2) =
                    f2bf(fmaxf(c[r] + bias, 0.f));
        }
    }
    __syncthreads();

    // L2: h2 = relu(h1 @ ow2^T + ob2), K=256
    {
        s16x8 ka[8];
#pragma unroll
        for (int ks = 0; ks < 8; ++ks)
            ka[ks] = *(const s16x8*)swzRc(h1A, l16, 512, ks * 64 + l4 * 16);
        const ushort* w2f = owbf + 32768;
#pragma unroll
        for (int ot = 0; ot < 2; ++ot) {
            const int otg = wave * 2 + ot;
            const int o = otg * 16 + l16;
            f32x4 c = (f32x4){0.f, 0.f, 0.f, 0.f};
#pragma unroll
            for (int ks = 0; ks < 8; ++ks) {
                s16x8 wb = *(const s16x8*)&w2f[((size_t)(otg * 8 + ks) * 64 + lane) * 8];
                c = MFMA16(ka[ks], wb, c);
            }
            const float bias = ob2[o];
#pragma unroll
            for (int r = 0; r < 4; ++r)
                *(ushort*)swzR(h2A, l4 * 4 + r, 512, o * 2) =
                    f2bf(fmaxf(c[r] + bias, 0.f));
        }
    }
    __syncthreads();

    // L3 + residual (f32 epilogue) on waves 0..3: d-tile = wave
    if (wave < 4) {
        s16x8 ka[8];
#pragma unroll
        for (int ks = 0; ks < 8; ++ks)
            ka[ks] = *(const s16x8*)swzRc(h2A, l16, 512, ks * 64 + l4 * 16);
        const ushort* w3f = owbf + 98304;
        const int d = wave * 16 + l16;
        f32x4 c = (f32x4){0.f, 0.f, 0.f, 0.f};
#pragma unroll
        for (int ks = 0; ks < 8; ++ks) {
            s16x8 wb = *(const s16x8*)&w3f[((size_t)(wave * 8 + ks) * 64 + lane) * 8];
            c = MFMA16(ka[ks], wb, c);
        }
        const float bias = ob3[d];
#pragma unroll
        for (int r = 0; r < 4; ++r) {
            const int n = n0 + l4 * 4 + r;
            const size_t idx = ((size_t)b * NN + n) * ND + d;
            out[idx] = inputs[idx] + c[r] + bias;
        }
    }
}

extern "C" void kernel_launch(void* const* d_in, const int* in_sizes, int n_in,
                              void* d_out, int out_size, void* d_ws, size_t ws_size,
                              hipStream_t stream)
{
    const float* inputs   = (const float*)d_in[0];
    const float* rel_rec  = (const float*)d_in[1];
    const float* rel_send = (const float*)d_in[2];
    const float* rel_type = (const float*)d_in[3];
    const float* w1  = (const float*)d_in[5];
    const float* b1  = (const float*)d_in[6];
    const float* w2  = (const float*)d_in[7];
    const float* b2  = (const float*)d_in[8];
    const float* w3  = (const float*)d_in[9];
    const float* b3  = (const float*)d_in[10];
    const float* w4  = (const float*)d_in[11];
    const float* b4  = (const float*)d_in[12];
    const float* ow1 = (const float*)d_in[13];
    const float* ob1 = (const float*)d_in[14];
    const float* ow2 = (const float*)d_in[15];
    const float* ob2 = (const float*)d_in[16];
    const float* ow3 = (const float*)d_in[17];
    const float* ob3 = (const float*)d_in[18];

    char* ws = (char*)d_ws;

    k_pre <<<dim3(256), dim3(256), 0, stream>>>(inputs, rel_rec, rel_send,
                                                w1, w3, ow1, ow2, ow3, ws);
    k_edge<<<dim3(256), dim3(512), 0, stream>>>(rel_type,
                                                b1, b2, b3, b4, w2, w4, ws);
    k_out <<<dim3(256), dim3(512), 0, stream>>>((const ushort*)ws,
                                                (const ushort*)(ws + WS_OW),
                                                inputs, ob1, ob2, ob3,
                                                (float*)d_out);
}

// Round 20
// 128.582 us; speedup vs baseline: 1.0218x; 1.0218x over previous
//
#include <hip/hip_runtime.h>
#include <hip/hip_bf16.h>

#define NB 32
#define NN 128
#define NE 16256
#define ND 64
#define NHID 128
#define NM 128
#define NOH 256
#define NT 2
#define EHALF 8128
#define NTILE 127        // 64-edge tiles per half (127*64 == 8128 exactly)
#define TILE_E 64

typedef short s16x8 __attribute__((ext_vector_type(8)));
typedef short s16x4 __attribute__((ext_vector_type(4)));
typedef float f32x4 __attribute__((ext_vector_type(4)));

#define MFMA16(a, b, c) __builtin_amdgcn_mfma_f32_16x16x32_bf16((a), (b), (c), 0, 0, 0)

// ---- ws layout (bytes) ----
// partial: bf16 [256][m=128][n=128]
#define PARTIAL_SZ ((size_t)256 * 128 * 128 * 2)          //  8,388,608
#define WS_RS      (PARTIAL_SZ)                           // ushort[NE][128]
#define RS_SZ      ((size_t)NE * 128 * 2)                 //  4,161,536
#define WS_RRT     (WS_RS + RS_SZ)                        // ushort[128][NE]
#define RRT_SZ     ((size_t)128 * NE * 2)                 //  4,161,536
#define WS_IWA     (WS_RRT + RRT_SZ)                      // ushort[b][half][it][h=128][n=128]
#define IWA_SZ     ((size_t)NB * 2 * 2 * 128 * 128 * 2)   //  8,388,608
#define WS_OW      (WS_IWA + IWA_SZ)                      // frag-ordered bf16 node weights
#define OW_SZ      ((size_t)(32768 + 65536 + 16384) * 2)  //    229,376
// total = 25.3 MB (<= proven 32 MB)

__device__ __forceinline__ ushort f2bf(float x) {
    uint u = __float_as_uint(x);
    return (ushort)((u + 0x7fffu + ((u >> 16) & 1u)) >> 16);
}
__device__ __forceinline__ float bf2f(ushort h) {
    return __uint_as_float(((uint)h) << 16);
}
__device__ __forceinline__ float4 ldg4(const float* p) {
    return *reinterpret_cast<const float4*>(p);
}
// pack 2 f32 -> 2 bf16 in one dword (RNE), single VALU op; low word = first arg
__device__ __forceinline__ uint cvtpk(float lo, float hi) {
    uint r;
    asm("v_cvt_pk_bf16_f32 %0, %1, %2" : "=v"(r) : "v"(lo), "v"(hi));
    return r;
}
__device__ __forceinline__ ushort f2bf1(float x) {   // single value via cvt_pk
    return (ushort)cvtpk(x, 0.f);
}
// pack 8 f32 (two float4) -> s16x8 bf16 via cvt_pk (uint4 is addressable)
__device__ __forceinline__ s16x8 pack8(float4 u, float4 v) {
    uint4 o;
    o.x = cvtpk(u.x, u.y);
    o.y = cvtpk(u.z, u.w);
    o.z = cvtpk(v.x, v.y);
    o.w = cvtpk(v.z, v.w);
    return *(s16x8*)&o;
}
// full-granule XOR swizzle for 256B rows: byte ^= (row&15)<<4
__device__ __forceinline__ char* swz16(void* base, int row, int bir) {
    return (char*)base + row * 256 + (bir ^ ((row & 15) << 4));
}
__device__ __forceinline__ const char* swz16c(const void* base, int row, int bir) {
    return (const char*)base + row * 256 + (bir ^ ((row & 15) << 4));
}
// 8-granule XOR swizzle for 128B rows: byte ^= (row&7)<<4
__device__ __forceinline__ char* swz8(void* base, int row, int bir) {
    return (char*)base + row * 128 + (bir ^ ((row & 7) << 4));
}
__device__ __forceinline__ const char* swz8c(const void* base, int row, int bir) {
    return (const char*)base + row * 128 + (bir ^ ((row & 7) << 4));
}
// generic-rowBytes variant (k_out buffers)
__device__ __forceinline__ char* swzR(void* base, int row, int rowBytes, int bir) {
    return (char*)base + row * rowBytes + (bir ^ ((row & 15) << 4));
}
__device__ __forceinline__ const char* swzRc(const void* base, int row, int rowBytes, int bir) {
    return (const char*)base + row * rowBytes + (bir ^ ((row & 15) << 4));
}
// async 16B global->LDS (dest lane-linear; source pre-swizzled per G21)
__device__ __forceinline__ void gload16(const void* g, void* l) {
    __builtin_amdgcn_global_load_lds(
        (const __attribute__((address_space(1))) void*)g,
        (__attribute__((address_space(3))) void*)l, 16, 0, 0);
}

// ---------------------------------------------------------------------------
// k_pre: balanced 256-block grid (1 block/CU, no straggler round).
// blocks 0..63:   rrT transpose, 2 eb each (127 total)
// blocks 64..95:  rs convert, 4 eb each
// blocks 96..223: inpWA precompute (128)
// blocks 224..255: node weights frag-order, 32 slices
// ---------------------------------------------------------------------------
__global__ __launch_bounds__(256)
void k_pre(const float* __restrict__ inputs,
           const float* __restrict__ rel_rec, const float* __restrict__ rel_send,
           const float* __restrict__ w1, const float* __restrict__ w3,
           const float* __restrict__ ow1, const float* __restrict__ ow2,
           const float* __restrict__ ow3,
           char* __restrict__ ws)
{
    ushort* rs  = (ushort*)(ws + WS_RS);
    ushort* rrT = (ushort*)(ws + WS_RRT);
    const int t = threadIdx.x;
    const int blk = blockIdx.x;

    if (blk < 64) {                        // rrT: 1-pass transpose, 2 eb/block
        __shared__ ushort tl[128][130];    // pad 2 -> 260B rows
        for (int rep = 0; rep < 2; ++rep) {
            const int eb = blk * 2 + rep;
            if (eb >= 127) break;          // uniform across block
            if (rep) __syncthreads();      // protect tl reuse
            for (int i = t; i < 4096; i += 256) {
                const int e = i >> 5, nq = i & 31;
                float4 v = ldg4(rel_rec + (size_t)(eb * 128 + e) * 128 + nq * 4);
                uint2 o;
                o.x = cvtpk(v.x, v.y);
                o.y = cvtpk(v.z, v.w);
                *(uint2*)&tl[e][nq * 4] = o;
            }
            __syncthreads();
            const int n = t >> 1, part = t & 1;
            for (int c = 0; c < 8; ++c) {
                const int e0 = part * 64 + c * 8;
                s16x8 v;
#pragma unroll
                for (int j = 0; j < 8; ++j) v[j] = (short)tl[e0 + j][n];
                *(s16x8*)&rrT[(size_t)n * NE + eb * 128 + e0] = v;
            }
        }
    } else if (blk < 96) {                 // rs: straight convert, 4 eb/block
        for (int j = 0; j < 4; ++j) {
            const int eb = (blk - 64) * 4 + j;
            if (eb >= 127) break;
            const float4* src = (const float4*)(rel_send + (size_t)eb * 16384);
            for (int i = t; i < 4096; i += 256) {
                float4 v = src[i];
                uint2 o;
                o.x = cvtpk(v.x, v.y);
                o.y = cvtpk(v.z, v.w);
                *(uint2*)(rs + (size_t)eb * 16384 + (size_t)i * 4) = o;
            }
        }
    } else if (blk < 224) {                // inpWA precompute (MFMA)
        ushort* iwa = (ushort*)(ws + WS_IWA);
        const int wg = blk - 96;           // 0..127
        const int b = wg >> 2, half = (wg >> 1) & 1, it = wg & 1;
        const float* WA  = (half ? w3 : w1) + (size_t)it * NHID * ND;
        const float* inp = inputs + (size_t)b * NN * ND;
        ushort* dst = iwa + (size_t)wg * NHID * NN;    // [h][n]

        const int lane = t & 63, wave = t >> 6;
        const int l16 = lane & 15, l4 = lane >> 4;

        for (int hh = 0; hh < 2; ++hh) {
            const int ht = wave * 2 + hh;
            s16x8 bf[2];
#pragma unroll
            for (int ks = 0; ks < 2; ++ks) {
                const float* p = WA + (size_t)(ht * 16 + l16) * ND + ks * 32 + l4 * 8;
                bf[ks] = pack8(ldg4(p), ldg4(p + 4));
            }
            for (int nt = 0; nt < 8; ++nt) {
                s16x8 af[2];
#pragma unroll
                for (int ks = 0; ks < 2; ++ks) {
                    const float* p = inp + (size_t)(nt * 16 + l16) * ND + ks * 32 + l4 * 8;
                    af[ks] = pack8(ldg4(p), ldg4(p + 4));
                }
                f32x4 c = (f32x4){0.f, 0.f, 0.f, 0.f};
                c = MFMA16(af[0], bf[0], c);
                c = MFMA16(af[1], bf[1], c);
                uint2 o;
                o.x = cvtpk(c[0], c[1]);
                o.y = cvtpk(c[2], c[3]);
                *(uint2*)&dst[(size_t)(ht * 16 + l16) * NN + nt * 16 + l4 * 4] = o;
            }
        }
    } else {                               // node weights -> bf16, 32 slices
        ushort* owbf = (ushort*)(ws + WS_OW);
        const int sl = blk - 224;          // 0..31
        if (t < 128) {
            const int i = sl * 128 + t;
            const int ln = i & 63, ks = (i >> 6) & 3, ot = i >> 8;
            const float* src = ow1 + (size_t)(ot * 16 + (ln & 15)) * 128 + ks * 32 + (ln >> 4) * 8;
            ushort* d = owbf + (size_t)i * 8;
#pragma unroll
            for (int j = 0; j < 8; ++j) d[j] = f2bf(src[j]);
        }
        {
            const int i = sl * 256 + t;
            const int ln = i & 63, ks = (i >> 6) & 7, ot = i >> 9;
            const float* src = ow2 + (size_t)(ot * 16 + (ln & 15)) * 256 + ks * 32 + (ln >> 4) * 8;
            ushort* d = owbf + 32768 + (size_t)i * 8;
#pragma unroll
            for (int j = 0; j < 8; ++j) d[j] = f2bf(src[j]);
        }
        if (t < 64) {
            const int i = sl * 64 + t;
            const int ln = i & 63, ks = (i >> 6) & 7, dt = i >> 9;
            const float* src = ow3 + (size_t)(dt * 16 + (ln & 15)) * 256 + ks * 32 + (ln >> 4) * 8;
            ushort* d = owbf + 98304 + (size_t)i * 8;
#pragma unroll
            for (int j = 0; j < 8; ++j) d[j] = f2bf(src[j]);
        }
    }
}

// ---------------------------------------------------------------------------
// k_edge: it-split + swapped H-GEMM (proven best, 111 us; reproduced twice).
// grid 256 = b*8 + half*4 + chunk(4), block 512.
// ---------------------------------------------------------------------------
__global__ __launch_bounds__(512, 1)
void k_edge(const float* __restrict__ rel_type,
            const float* __restrict__ b1, const float* __restrict__ b2,
            const float* __restrict__ b3, const float* __restrict__ b4,
            const float* __restrict__ w2, const float* __restrict__ w4,
            char* __restrict__ ws)
{
    const ushort* rsg = (const ushort*)(ws + WS_RS);
    const ushort* rrT = (const ushort*)(ws + WS_RRT);
    const ushort* iwa = (const ushort*)(ws + WS_IWA);
    ushort* partial   = (ushort*)ws;

    const int tid  = threadIdx.x;
    const int wave = tid >> 6;
    const int lane = tid & 63;
    const int l16  = lane & 15;
    const int l4   = lane >> 4;
    const int wi   = wave & 1;     // it for H/M phases
    const int wg2  = wave >> 1;    // 32-col block for H/M phases
    const int wn   = wave & 3;     // agg: n-block (32 rows)
    const int wm2  = wave >> 2;    // agg: m-half (64 cols)

    const int wg    = blockIdx.x;
    const int b     = wg >> 3;
    const int half  = (wg >> 2) & 1;
    const int chunk = wg & 3;

    const float* BA    = half ? b3 : b1;
    const float* BB    = half ? b4 : b2;
    const float* WBsrc = half ? w4 : w2;

    __shared__ ushort H_s[2][64 * 128];     // 32 KB [it][e][h], 256B rows
    __shared__ ushort rs_s[2][64 * 128];    // 32 KB, 256B rows
    __shared__ ushort rr_s[2][128 * 64];    // 32 KB, 128B rows
    __shared__ ushort Mt_s[2][128 * 64];    // 32 KB [it][m][e], 128B rows
    __shared__ float  rt_s[2][128];         //  1 KB

    // persistent fragments: wIW 32 (only it=wi) + wB 32 (only it=wi) + agg 32
    s16x8 wIW[2][4];   // [ht][ks]: A-frag rows h = wg2*32 + ht*16 + l16, k=n
    {
        const ushort* iwb = iwa + (size_t)((b * 2 + half) * 2 + wi) * NHID * NN;
#pragma unroll
        for (int ht = 0; ht < 2; ++ht)
#pragma unroll
            for (int ks = 0; ks < 4; ++ks)
                wIW[ht][ks] = *(const s16x8*)(iwb +
                    (size_t)(wg2 * 32 + ht * 16 + l16) * NN + ks * 32 + l4 * 8);
    }
    s16x8 wB[2][4];    // [mt][ks], m = wg2*32 + mt*16 + l16, it = wi
#pragma unroll
    for (int mt = 0; mt < 2; ++mt)
#pragma unroll
        for (int ks = 0; ks < 4; ++ks) {
            const float* p = WBsrc +
                (size_t)(wi * NM + wg2 * 32 + mt * 16 + l16) * NHID + ks * 32 + l4 * 8;
            wB[mt][ks] = pack8(ldg4(p), ldg4(p + 4));
        }
    // biasA per-reg (h = wg2*32 + ht*16 + l4*4 + r) as float4; biasB per-lane
    float4 bA[2];
#pragma unroll
    for (int ht = 0; ht < 2; ++ht)
        bA[ht] = ldg4(BA + wi * NHID + wg2 * 32 + ht * 16 + l4 * 4);
    float biasB[2];
#pragma unroll
    for (int q = 0; q < 2; ++q)
        biasB[q] = BB[wi * NM + wg2 * 32 + q * 16 + l16];

    f32x4 agg[2][4];   // [nt][mt]: rows wn*32+nt*16, cols wm2*64+mt*16
#pragma unroll
    for (int i = 0; i < 2; ++i)
#pragma unroll
        for (int j = 0; j < 4; ++j) agg[i][j] = (f32x4){0.f, 0.f, 0.f, 0.f};

    const int t0 = chunk * 32;
    const int t1 = (t0 + 32 < NTILE) ? (t0 + 32) : NTILE;

    // ---- prologue: stage rs(t0) into buf0 ----
    {
        const int ebase0 = half * EHALF + t0 * TILE_E;
#pragma unroll
        for (int s = 0; s < 2; ++s) {
            const int i = s * 512 + tid;
            const int e = i >> 4, c = i & 15;
            const int cp = c ^ (e & 15);
            gload16(rsg + (size_t)(ebase0 + e) * 128 + cp * 8, (char*)&rs_s[0][0] + i * 16);
        }
    }
    __syncthreads();

    for (int t = t0; t < t1; ++t) {
        const int buf  = (t - t0) & 1;
        const int nbuf = buf ^ 1;
        const int ebase = half * EHALF + t * TILE_E;
        const bool do_next = (t + 1) < t1;

        // ---- P(t): staging issues + H phase ----
#pragma unroll
        for (int s = 0; s < 2; ++s) {
            const int j = s * 512 + tid;
            const int n = j >> 3, c = j & 7;
            const int cp = c ^ (n & 7);
            gload16(rrT + (size_t)n * NE + ebase + cp * 8, (char*)&rr_s[buf][0] + j * 16);
        }
        if (do_next) {
            const int ebn = ebase + TILE_E;
#pragma unroll
            for (int s = 0; s < 2; ++s) {
                const int i = s * 512 + tid;
                const int e = i >> 4, c = i & 15;
                const int cp = c ^ (e & 15);
                gload16(rsg + (size_t)(ebn + e) * 128 + cp * 8, (char*)&rs_s[nbuf][0] + i * 16);
            }
        }
        if (tid < 128)
            rt_s[buf][tid] = rel_type[((size_t)b * NE + ebase + (tid >> 1)) * NT + (tid & 1)];

        // H phase (SWAPPED): C[h][e] = mfma(A=wIW, B=rs); lane: col e = l16,
        // rows h = wg2*32 + ht*16 + l4*4 + r  -> uint2 write, h-contiguous
#pragma unroll
        for (int et = 0; et < 4; ++et) {
            const int erow = et * 16 + l16;
            s16x8 rb0 = *(const s16x8*)swz16c(&rs_s[buf][0], erow, 0 * 64 + l4 * 16);
            s16x8 rb1 = *(const s16x8*)swz16c(&rs_s[buf][0], erow, 1 * 64 + l4 * 16);
            s16x8 rb2 = *(const s16x8*)swz16c(&rs_s[buf][0], erow, 2 * 64 + l4 * 16);
            s16x8 rb3 = *(const s16x8*)swz16c(&rs_s[buf][0], erow, 3 * 64 + l4 * 16);
#pragma unroll
            for (int ht = 0; ht < 2; ++ht) {
                f32x4 c = (f32x4){0.f, 0.f, 0.f, 0.f};
                __builtin_amdgcn_s_setprio(1);
                c = MFMA16(wIW[ht][0], rb0, c);
                c = MFMA16(wIW[ht][1], rb1, c);
                c = MFMA16(wIW[ht][2], rb2, c);
                c = MFMA16(wIW[ht][3], rb3, c);
                __builtin_amdgcn_s_setprio(0);
                uint2 v;
                v.x = cvtpk(fmaxf(c[0] + bA[ht].x, 0.f), fmaxf(c[1] + bA[ht].y, 0.f));
                v.y = cvtpk(fmaxf(c[2] + bA[ht].z, 0.f), fmaxf(c[3] + bA[ht].w, 0.f));
                *(uint2*)swz16(&H_s[wi][0], erow, (wg2 * 32 + ht * 16 + l4 * 4) * 2) = v;
            }
        }
        __syncthreads();                                   // bar1

        // ---- M(t): Mpart[wi][:, wg2*32..+32]; reads only H[wi] ----
#pragma unroll
        for (int et = 0; et < 4; ++et) {
            const int e = et * 16 + l16;
            s16x8 a0 = *(const s16x8*)swz16c(&H_s[wi][0], e, 0 * 64 + l4 * 16);
            s16x8 a1 = *(const s16x8*)swz16c(&H_s[wi][0], e, 1 * 64 + l4 * 16);
            s16x8 a2 = *(const s16x8*)swz16c(&H_s[wi][0], e, 2 * 64 + l4 * 16);
            s16x8 a3 = *(const s16x8*)swz16c(&H_s[wi][0], e, 3 * 64 + l4 * 16);
            float rtv[4];
#pragma unroll
            for (int r = 0; r < 4; ++r)
                rtv[r] = rt_s[buf][(et * 16 + l4 * 4 + r) * 2 + wi];
#pragma unroll
            for (int mt = 0; mt < 2; ++mt) {
                f32x4 c = (f32x4){0.f, 0.f, 0.f, 0.f};
                __builtin_amdgcn_s_setprio(1);
                c = MFMA16(a0, wB[mt][0], c);
                c = MFMA16(a1, wB[mt][1], c);
                c = MFMA16(a2, wB[mt][2], c);
                c = MFMA16(a3, wB[mt][3], c);
                __builtin_amdgcn_s_setprio(0);
                const int m = wg2 * 32 + mt * 16 + l16;
                uint2 v;
                v.x = cvtpk(fmaxf(c[0] + biasB[mt], 0.f) * rtv[0],
                            fmaxf(c[1] + biasB[mt], 0.f) * rtv[1]);
                v.y = cvtpk(fmaxf(c[2] + biasB[mt], 0.f) * rtv[2],
                            fmaxf(c[3] + biasB[mt], 0.f) * rtv[3]);
                *(uint2*)swz8(&Mt_s[wi][0], m, et * 32 + l4 * 8) = v;
            }
        }
        __syncthreads();                                   // bar2

        // ---- agg(t): agg += rrT@Mt[0] + rrT@Mt[1]  (32n x 64m per wave) ----
#pragma unroll
        for (int ks = 0; ks < 2; ++ks) {
            s16x8 aa0 = *(const s16x8*)swz8c(&rr_s[buf][0], wn * 32 + 0 * 16 + l16, ks * 64 + l4 * 16);
            s16x8 aa1 = *(const s16x8*)swz8c(&rr_s[buf][0], wn * 32 + 1 * 16 + l16, ks * 64 + l4 * 16);
#pragma unroll
            for (int it = 0; it < 2; ++it) {
                __builtin_amdgcn_s_setprio(1);
#pragma unroll
                for (int mt = 0; mt < 4; ++mt) {
                    s16x8 bb = *(const s16x8*)swz8c(&Mt_s[it][0],
                        wm2 * 64 + mt * 16 + l16, ks * 64 + l4 * 16);
                    agg[0][mt] = MFMA16(aa0, bb, agg[0][mt]);
                    agg[1][mt] = MFMA16(aa1, bb, agg[1][mt]);
                }
                __builtin_amdgcn_s_setprio(0);
            }
        }
    }

    // store bf16 partialT [wg][m][n]
    {
        ushort* dst = partial + (size_t)wg * (NN * NM);
#pragma unroll
        for (int nt = 0; nt < 2; ++nt)
#pragma unroll
            for (int mt = 0; mt < 4; ++mt) {
                const int m  = wm2 * 64 + mt * 16 + l16;
                const int n0 = wn * 32 + nt * 16 + l4 * 4;
                uint2 v;
                v.x = cvtpk(agg[nt][mt][0], agg[nt][mt][1]);
                v.y = cvtpk(agg[nt][mt][2], agg[nt][mt][3]);
                *(uint2*)&dst[(size_t)m * NN + n0] = v;
            }
    }
}

// ---------------------------------------------------------------------------
// k_out: MFMA node MLP, 512 threads (8 waves, 2/SIMD), frag-ordered weights.
// grid 256 = b*8 + ng (16 n-rows). L1/L2: wave owns 2 o-tiles; L3: waves 0-3.
// ---------------------------------------------------------------------------
__global__ __launch_bounds__(512)
void k_out(const ushort* __restrict__ partial,
           const ushort* __restrict__ owbf,
           const float* __restrict__ inputs,
           const float* __restrict__ ob1, const float* __restrict__ ob2,
           const float* __restrict__ ob3,
           float* __restrict__ out)
{
    const int t    = threadIdx.x;
    const int wave = t >> 6;
    const int lane = t & 63;
    const int l16  = lane & 15;
    const int l4   = lane >> 4;
    const int wg   = blockIdx.x;
    const int b    = wg >> 3;
    const int n0   = (wg & 7) * 16;

    __shared__ ushort xA[16 * 128];    // 4 KB  [n][m], 256B rows
    __shared__ ushort h1A[16 * 256];   // 8 KB  [n][o], 512B rows
    __shared__ ushort h2A[16 * 256];   // 8 KB

    // reduce 8 bf16 partials -> xA (512 threads cover all 128m x 4 n-quads)
    {
        const int m = t >> 2, g = t & 3;
        float s0 = 0.f, s1 = 0.f, s2 = 0.f, s3 = 0.f;
#pragma unroll
        for (int c = 0; c < 8; ++c) {
            const ushort* p = partial + ((size_t)(b * 8 + c)) * (NN * NM) +
                              (size_t)m * NN + n0 + g * 4;
            s16x4 v = *(const s16x4*)p;
            s0 += bf2f((ushort)v[0]); s1 += bf2f((ushort)v[1]);
            s2 += bf2f((ushort)v[2]); s3 += bf2f((ushort)v[3]);
        }
        *(ushort*)swzR(xA, g * 4 + 0, 256, m * 2) = f2bf(s0);
        *(ushort*)swzR(xA, g * 4 + 1, 256, m * 2) = f2bf(s1);
        *(ushort*)swzR(xA, g * 4 + 2, 256, m * 2) = f2bf(s2);
        *(ushort*)swzR(xA, g * 4 + 3, 256, m * 2) = f2bf(s3);
    }
    __syncthreads();

    // L1: h1 = relu(x @ ow1^T + ob1); wave owns o-tiles {wave*2, wave*2+1}
    {
        s16x8 ka[4];
#pragma unroll
        for (int ks = 0; ks < 4; ++ks)
            ka[ks] = *(const s16x8*)swzRc(xA, l16, 256, ks * 64 + l4 * 16);
#pragma unroll
        for (int ot = 0; ot < 2; ++ot) {
            const int otg = wave * 2 + ot;
            const int o = otg * 16 + l16;
            f32x4 c = (f32x4){0.f, 0.f, 0.f, 0.f};
#pragma unroll
            for (int ks = 0; ks < 4; ++ks) {
                s16x8 wb = *(const s16x8*)&owbf[((size_t)(otg * 4 + ks) * 64 + lane) * 8];
                c = MFMA16(ka[ks], wb, c);
            }
            const float bias = ob1[o];
#pragma unroll
            for (int r = 0; r < 4; ++r)
                *(ushort*)swzR(h1A, l4 * 4 + r, 512, o * 2) =
                    f2bf(fmaxf(c[r] + bias, 0.f));
        }
    }
    __syncthreads();

    // L2: h2 = relu(h1 @ ow2^T + ob2), K=256
    {
        s16x8 ka[8];
#pragma unroll
        for (int ks = 0; ks < 8; ++ks)
            ka[ks] = *(const s16x8*)swzRc(h1A, l16, 512, ks * 64 + l4 * 16);
        const ushort* w2f = owbf + 32768;
#pragma unroll
        for (int ot = 0; ot < 2; ++ot) {
            const int otg = wave * 2 + ot;
            const int o = otg * 16 + l16;
            f32x4 c = (f32x4){0.f, 0.f, 0.f, 0.f};
#pragma unroll
            for (int ks = 0; ks < 8; ++ks) {
                s16x8 wb = *(const s16x8*)&w2f[((size_t)(otg * 8 + ks) * 64 + lane) * 8];
                c = MFMA16(ka[ks], wb, c);
            }
            const float bias = ob2[o];
#pragma unroll
            for (int r = 0; r < 4; ++r)
                *(ushort*)swzR(h2A, l4 * 4 + r, 512, o * 2) =
                    f2bf(fmaxf(c[r] + bias, 0.f));
        }
    }
    __syncthreads();

    // L3 + residual (f32 epilogue) on waves 0..3: d-tile = wave
    if (wave < 4) {
        s16x8 ka[8];
#pragma unroll
        for (int ks = 0; ks < 8; ++ks)
            ka[ks] = *(const s16x8*)swzRc(h2A, l16, 512, ks * 64 + l4 * 16);
        const ushort* w3f = owbf + 98304;
        const int d = wave * 16 + l16;
        f32x4 c = (f32x4){0.f, 0.f, 0.f, 0.f};
#pragma unroll
        for (int ks = 0; ks < 8; ++ks) {
            s16x8 wb = *(const s16x8*)&w3f[((size_t)(wave * 8 + ks) * 64 + lane) * 8];
            c = MFMA16(ka[ks], wb, c);
        }
        const float bias = ob3[d];
#pragma unroll
        for (int r = 0; r < 4; ++r) {
            const int n = n0 + l4 * 4 + r;
            const size_t idx = ((size_t)b * NN + n) * ND + d;
            out[idx] = inputs[idx] + c[r] + bias;
        }
    }
}

extern "C" void kernel_launch(void* const* d_in, const int* in_sizes, int n_in,
                              void* d_out, int out_size, void* d_ws, size_t ws_size,
                              hipStream_t stream)
{
    const float* inputs   = (const float*)d_in[0];
    const float* rel_rec  = (const float*)d_in[1];
    const float* rel_send = (const float*)d_in[2];
    const float* rel_type = (const float*)d_in[3];
    const float* w1  = (const float*)d_in[5];
    const float* b1  = (const float*)d_in[6];
    const float* w2  = (const float*)d_in[7];
    const float* b2  = (const float*)d_in[8];
    const float* w3  = (const float*)d_in[9];
    const float* b3  = (const float*)d_in[10];
    const float* w4  = (const float*)d_in[11];
    const float* b4  = (const float*)d_in[12];
    const float* ow1 = (const float*)d_in[13];
    const float* ob1 = (const float*)d_in[14];
    const float* ow2 = (const float*)d_in[15];
    const float* ob2 = (const float*)d_in[16];
    const float* ow3 = (const float*)d_in[17];
    const float* ob3 = (const float*)d_in[18];

    char* ws = (char*)d_ws;

    k_pre <<<dim3(256), dim3(256), 0, stream>>>(inputs, rel_rec, rel_send,
                                                w1, w3, ow1, ow2, ow3, ws);
    k_edge<<<dim3(256), dim3(512), 0, stream>>>(rel_type,
                                                b1, b2, b3, b4, w2, w4, ws);
    k_out <<<dim3(256), dim3(512), 0, stream>>>((const ushort*)ws,
                                                (const ushort*)(ws + WS_OW),
                                                inputs, ob1, ob2, ob3,
                                                (float*)d_out);
}